// Round 12
// baseline (400.912 us; speedup 1.0000x reference)
//
#include <hip/hip_runtime.h>

#define NB 16
#define NN 256
#define DD 128
#define NL 3
#define NE 32768
#define BN 4096   // NB*NN

// ---------------- helpers ----------------
__device__ __forceinline__ float siluf(float y) {
  return __fdividef(y, 1.0f + __expf(-y));
}

template<int CTRL>
__device__ __forceinline__ float dpp_add(float x) {
  int v = __builtin_amdgcn_update_dpp(0, __float_as_int(x), CTRL, 0xF, 0xF, true);
  return x + __int_as_float(v);
}

__device__ __forceinline__ float sum16(float x) {
  x = dpp_add<0xB1>(x);
  x = dpp_add<0x4E>(x);
  x = dpp_add<0x141>(x);
  x = dpp_add<0x140>(x);
  return x;
}

__device__ __forceinline__ float sum32(float x) {
  x = sum16(x);
  int v = __builtin_amdgcn_ds_swizzle(__float_as_int(x), 0x401F); // xor 16
  return x + __int_as_float(v);
}

__device__ __forceinline__ float sum64(float x) {
  x = sum32(x);
  return x + __shfl_xor(x, 32, 64);
}

// ---------------- kernels ----------------

// fused: zero adj + encode h + wprep stats
__global__ __launch_bounds__(256) void k_pre(
    const float* __restrict__ x, const float* __restrict__ encW,
    const float* __restrict__ encb, const float* __restrict__ msgW,
    float* __restrict__ h, float* __restrict__ adj, float* __restrict__ wst) {
  int t = blockIdx.x * 256 + threadIdx.x;
  float4 z = make_float4(0.f, 0.f, 0.f, 0.f);
  float4* a4 = (float4*)adj;
  a4[t] = z;
  a4[t + 131072] = z;
  int i = t >> 5;
  int c = (t & 31) << 2;
  float xv = x[i];
  float4 w = *(const float4*)(encW + c);
  float4 bv = *(const float4*)(encb + c);
  float4 o;
  o.x = fmaf(xv, w.x, bv.x); o.y = fmaf(xv, w.y, bv.y);
  o.z = fmaf(xv, w.z, bv.z); o.w = fmaf(xv, w.w, bv.w);
  *(float4*)(h + (size_t)i * DD + c) = o;
  if (blockIdx.x < NL && threadIdx.x < 64) {
    int l = blockIdx.x;
    const float* wj = msgW + (size_t)l * (2 * DD + 1) * DD + 2 * DD * DD;
    int d0 = threadIdx.x << 1;
    float2 wv = *(const float2*)(wj + d0);
    float s1 = sum64(wv.x + wv.y);
    float s2 = sum64(fmaf(wv.x, wv.x, wv.y * wv.y));
    if (threadIdx.x == 0)
      *(float2*)(wst + 2 * l) = make_float2(s1 * 0.0078125f, s2 * 0.0078125f);
  }
}

__global__ __launch_bounds__(256) void k_scatter(
    const int* __restrict__ ei, const float* __restrict__ ea,
    float* __restrict__ adj) {
  int e = blockIdx.x * 256 + threadIdx.x;
  int g0 = ei[e];
  int g1 = ei[NE + e];
  float v = ea[e];
  int b = g0 >> 8;
  int s = g0 & 255;
  int d = g1 & 255;
  atomicAdd(adj + (b * NN + s) * NN + d, v);
  atomicAdd(adj + (b * NN + d) * NN + s, v);
}

// C1 = A@W1 (+bias1), C2 = A@W2; optional per-row stats vs wj.
// 512 threads = 8 waves, wave-per-row, float2/lane: 4 waves/SIMD occupancy,
// W rows reused across the 8 waves via L1.
__global__ __launch_bounds__(512) void k_gemm2(
    const float* __restrict__ A, const float* __restrict__ W1,
    const float* __restrict__ W2, const float* __restrict__ bias1,
    const float* __restrict__ wj,
    float* __restrict__ C1, float* __restrict__ C2,
    float* __restrict__ statT, float* __restrict__ statS) {
  __shared__ float sa[8][128];
  int t = threadIdx.x;
  int r = t >> 6;              // wave index = row
  int c2 = (t & 63) << 1;      // 2 cols per lane
  int row0 = blockIdx.x << 3;
  if (t < 256)
    ((float4*)sa)[t] = ((const float4*)(A + (size_t)row0 * DD))[t];
  __syncthreads();
  float2 a1 = {0.f, 0.f}, a2 = {0.f, 0.f};
  #pragma unroll 4
  for (int m = 0; m < DD; ++m) {
    float a = sa[r][m];
    float2 w1 = *(const float2*)(W1 + m * DD + c2);
    float2 w2 = *(const float2*)(W2 + m * DD + c2);
    a1.x = fmaf(a, w1.x, a1.x); a1.y = fmaf(a, w1.y, a1.y);
    a2.x = fmaf(a, w2.x, a2.x); a2.y = fmaf(a, w2.y, a2.y);
  }
  if (bias1) {
    float2 bv = *(const float2*)(bias1 + c2);
    a1.x += bv.x; a1.y += bv.y;
  }
  int rw = row0 + r;
  *(float2*)(C1 + (size_t)rw * DD + c2) = a1;
  *(float2*)(C2 + (size_t)rw * DD + c2) = a2;
  if (wj) {
    float2 wv = *(const float2*)(wj + c2);
    float s1t = sum64(a1.x + a1.y);
    float s2t = sum64(fmaf(a1.x, a1.x, a1.y * a1.y));
    float s3t = sum64(fmaf(a1.x, wv.x, a1.y * wv.y));
    float s1s = sum64(a2.x + a2.y);
    float s2s = sum64(fmaf(a2.x, a2.x, a2.y * a2.y));
    float s3s = sum64(fmaf(a2.x, wv.x, a2.y * wv.y));
    if ((t & 63) == 0) {
      const float inv = 0.0078125f;
      ((float4*)statT)[rw] = make_float4(s1t * inv, s2t * inv, s3t * inv, 0.f);
      ((float4*)statS)[rw] = make_float4(s1s * inv, s2s * inv, s3s * inv, 0.f);
    }
  }
}

// TS GEMM + closed-form LN moments: MR4[b,i,j] = (rstd, -mean*rstd, a, 0)
__global__ __launch_bounds__(256) void k_ts(
    const float* __restrict__ T, const float* __restrict__ S,
    const float* __restrict__ adj,
    const float* __restrict__ statT, const float* __restrict__ statS,
    const float* __restrict__ wst, float* __restrict__ MR4) {
  __shared__ float sT[64][64];  // k-major: sT[k][i]
  __shared__ float sS[64][64];
  int b = blockIdx.x >> 4;
  int i0 = ((blockIdx.x >> 2) & 3) << 6;
  int j0 = (blockIdx.x & 3) << 6;
  int t = threadIdx.x;
  int ti = t >> 4, tj = t & 15;
  float acc[4][4] = {};
  int sr = t >> 2, scg = t & 3;
  const float* Trow = T + ((size_t)(b * NN + i0 + sr)) * DD + scg * 16;
  const float* Srow = S + ((size_t)(b * NN + j0 + sr)) * DD + scg * 16;
  for (int kc = 0; kc < 2; ++kc) {
    __syncthreads();
    #pragma unroll
    for (int m = 0; m < 4; ++m) {
      float4 v = *(const float4*)(Trow + kc * 64 + m * 4);
      int kk = scg * 16 + m * 4;
      sT[kk + 0][sr] = v.x; sT[kk + 1][sr] = v.y;
      sT[kk + 2][sr] = v.z; sT[kk + 3][sr] = v.w;
      float4 u = *(const float4*)(Srow + kc * 64 + m * 4);
      sS[kk + 0][sr] = u.x; sS[kk + 1][sr] = u.y;
      sS[kk + 2][sr] = u.z; sS[kk + 3][sr] = u.w;
    }
    __syncthreads();
    #pragma unroll 4
    for (int k = 0; k < 64; ++k) {
      float4 rt = *(const float4*)&sT[k][ti << 2];
      float4 rs = *(const float4*)&sS[k][tj << 2];
      acc[0][0] = fmaf(rt.x, rs.x, acc[0][0]);
      acc[0][1] = fmaf(rt.x, rs.y, acc[0][1]);
      acc[0][2] = fmaf(rt.x, rs.z, acc[0][2]);
      acc[0][3] = fmaf(rt.x, rs.w, acc[0][3]);
      acc[1][0] = fmaf(rt.y, rs.x, acc[1][0]);
      acc[1][1] = fmaf(rt.y, rs.y, acc[1][1]);
      acc[1][2] = fmaf(rt.y, rs.z, acc[1][2]);
      acc[1][3] = fmaf(rt.y, rs.w, acc[1][3]);
      acc[2][0] = fmaf(rt.z, rs.x, acc[2][0]);
      acc[2][1] = fmaf(rt.z, rs.y, acc[2][1]);
      acc[2][2] = fmaf(rt.z, rs.z, acc[2][2]);
      acc[2][3] = fmaf(rt.z, rs.w, acc[2][3]);
      acc[3][0] = fmaf(rt.w, rs.x, acc[3][0]);
      acc[3][1] = fmaf(rt.w, rs.y, acc[3][1]);
      acc[3][2] = fmaf(rt.w, rs.z, acc[3][2]);
      acc[3][3] = fmaf(rt.w, rs.w, acc[3][3]);
    }
  }
  float2 ws = *(const float2*)wst;
  float4 stT[4], stS[4];
  #pragma unroll
  for (int o = 0; o < 4; ++o) {
    stT[o] = ((const float4*)statT)[b * NN + i0 + (ti << 2) + o];
    stS[o] = ((const float4*)statS)[b * NN + j0 + (tj << 2) + o];
  }
  #pragma unroll
  for (int oi = 0; oi < 4; ++oi) {
    int row = b * NN + i0 + (ti << 2) + oi;
    float4 av = *(const float4*)(adj + (size_t)row * NN + j0 + (tj << 2));
    float4* m4row = (float4*)MR4 + (size_t)row * NN + j0 + (tj << 2);
    #pragma unroll
    for (int oj = 0; oj < 4; ++oj) {
      float a = (oj == 0) ? av.x : (oj == 1) ? av.y : (oj == 2) ? av.z : av.w;
      float mean = stT[oi].x + stS[oj].x + a * ws.x;
      float e2 = stT[oi].y + stS[oj].y + a * a * ws.y
               + fmaf(acc[oi][oj], 0.015625f, 2.f * a * (stT[oi].z + stS[oj].z));
      float var = fmaf(-mean, mean, e2);
      float Rv = rsqrtf(var + 1e-5f);
      m4row[oj] = make_float4(Rv, -mean * Rv, a, 0.f);
    }
  }
}

// message body: given MR float4 (m4) and hs float4, accumulate silu terms.
#define MSG_BODY(m4, hs, SGN)                                   \
  do {                                                          \
    float v0 = fmaf((m4).z, wv.x, tv.x + (hs).x);               \
    float v1 = fmaf((m4).z, wv.y, tv.y + (hs).y);               \
    float v2 = fmaf((m4).z, wv.z, tv.z + (hs).z);               \
    float v3 = fmaf((m4).z, wv.w, tv.w + (hs).w);               \
    float z0 = fmaf((m4).x, v0, (m4).y);                        \
    float z1 = fmaf((m4).x, v1, (m4).y);                        \
    float z2 = fmaf((m4).x, v2, (m4).y);                        \
    float z3 = fmaf((m4).x, v3, (m4).y);                        \
    float y0 = fmaf(G0, z0, B0);                                \
    float y1 = fmaf(G1, z1, B1);                                \
    float y2 = fmaf(G2, z2, B2);                                \
    float y3 = fmaf(G3, z3, B3);                                \
    float e0 = __builtin_amdgcn_exp2f(-y0);                     \
    float e1 = __builtin_amdgcn_exp2f(-y1);                     \
    float e2 = __builtin_amdgcn_exp2f(-y2);                     \
    float e3 = __builtin_amdgcn_exp2f(-y3);                     \
    float d0v = 1.0f + e0, d1v = 1.0f + e1;                     \
    float d2v = 1.0f + e2, d3v = 1.0f + e3;                     \
    float r01 = __builtin_amdgcn_rcpf(d0v * d1v);               \
    float r23 = __builtin_amdgcn_rcpf(d2v * d3v);               \
    a0 = fmaf(y0 * d1v, (SGN) * r01, a0);                       \
    a1 = fmaf(y1 * d0v, (SGN) * r01, a1);                       \
    a2 = fmaf(y2 * d3v, (SGN) * r23, a2);                       \
    a3 = fmaf(y3 * d2v, (SGN) * r23, a3);                       \
  } while (0)

// messages + aggregation: 8 waves = 2 i-pairs x 4 contiguous 64-j slices.
// hs direct from global with a 4-deep register prefetch queue; MR from LDS;
// no barriers in the hot loop.
__global__ __launch_bounds__(512, 4) void k_messages(
    const float* __restrict__ hT, const float* __restrict__ hS,
    const float* __restrict__ MR4, const float* __restrict__ wj,
    const float* __restrict__ mg, const float* __restrict__ mbe,
    float* __restrict__ agg) {
  __shared__ float4 smr[4 * 256];    // 16 KB: MR for 4 i x 256 j (then merge buf)
  const float LN2 = 0.6931471805599453f;
  const float L2E = 1.4426950408889634f;
  int b = blockIdx.x >> 6;
  int i0 = (blockIdx.x & 63) << 2;   // 4 i per block
  int t = threadIdx.x;
  int w = t >> 6, lane = t & 63;
  int p = w >> 2;                    // i-pair 0..1
  int q = w & 3;                     // 64-j slice 0..3
  int half = lane >> 5, li = lane & 31;
  int iloc = (p << 1) + half;
  int i = i0 + iloc;
  int row = b * NN + i;
  int d0 = li << 2;                  // 4 d's per lane
  float4 tv = *(const float4*)(hT + (size_t)row * DD + d0);  // includes mb
  float4 wv = *(const float4*)(wj + d0);
  float4 gv = *(const float4*)(mg + d0);
  float4 be = *(const float4*)(mbe + d0);
  float G0 = gv.x * L2E, G1 = gv.y * L2E, G2 = gv.z * L2E, G3 = gv.w * L2E;
  float B0 = be.x * L2E, B1 = be.y * L2E, B2 = be.z * L2E, B3 = be.w * L2E;
  float a0 = 0.f, a1 = 0.f, a2 = 0.f, a3 = 0.f;

  {  // stage MR for 4 i's: 1024 float4, 2 per thread (coalesced)
    const float4* msrc = (const float4*)MR4 + (size_t)(b * NN + i0) * NN;
    smr[t] = msrc[t];
    smr[t + 512] = msrc[t + 512];
  }
  __syncthreads();

  const float4* mrow = smr + (iloc << 8) + (q << 6);
  const float4* hrow = (const float4*)(hS + (size_t)(b * NN + (q << 6)) * DD) + li;

  // 4-deep register prefetch queue for hs
  float4 hsq[4];
  hsq[0] = hrow[0];
  hsq[1] = hrow[1 << 5];
  hsq[2] = hrow[2 << 5];
  hsq[3] = hrow[3 << 5];
  #pragma unroll 4
  for (int jj = 0; jj < 60; ++jj) {
    float4 hs = hsq[jj & 3];
    hsq[jj & 3] = hrow[(jj + 4) << 5];
    float4 m4 = mrow[jj];
    MSG_BODY(m4, hs, 1.0f);
  }
  #pragma unroll
  for (int jj = 60; jj < 64; ++jj) {
    float4 hs = hsq[jj & 3];
    float4 m4 = mrow[jj];
    MSG_BODY(m4, hs, 1.0f);
  }
  if ((i >> 6) == q) {  // subtract j == i (uniform per half-wave)
    float4 m4 = smr[(iloc << 8) + i];
    float4 hs = ((const float4*)(hS + (size_t)(b * NN + i) * DD))[li];
    MSG_BODY(m4, hs, -1.0f);
  }
  __syncthreads();  // all smr reads done; reuse as merge buffer
  float4* smg = (float4*)smr;
  smg[(((iloc << 2) + q) << 5) + li] = make_float4(a0, a1, a2, a3);
  __syncthreads();
  if (t < 128) {
    int il2 = t >> 5, l2 = t & 31;
    float4 s0 = smg[(((il2 << 2) + 0) << 5) + l2];
    float4 s1 = smg[(((il2 << 2) + 1) << 5) + l2];
    float4 s2 = smg[(((il2 << 2) + 2) << 5) + l2];
    float4 s3 = smg[(((il2 << 2) + 3) << 5) + l2];
    float4 o;
    o.x = ((s0.x + s1.x) + (s2.x + s3.x)) * LN2;
    o.y = ((s0.y + s1.y) + (s2.y + s3.y)) * LN2;
    o.z = ((s0.z + s1.z) + (s2.z + s3.z)) * LN2;
    o.w = ((s0.w + s1.w) + (s2.w + s3.w)) * LN2;
    *(float4*)(agg + (size_t)(b * NN + i0 + il2) * DD + (l2 << 2)) = o;
  }
}

// u = [h|agg] @ W + ub;  h += silu(LN(u))
// 512 threads = 8 waves, wave-per-row, float2/lane (4 waves/SIMD).
__global__ __launch_bounds__(512) void k_update(
    float* __restrict__ h, const float* __restrict__ agg,
    const float* __restrict__ W, const float* __restrict__ ub,
    const float* __restrict__ ug, const float* __restrict__ ube) {
  __shared__ float scat[8][256];
  int t = threadIdx.x;
  int r = t >> 6;
  int c2 = (t & 63) << 1;
  int row0 = blockIdx.x << 3;
  {
    int rr = t >> 6;
    int mm = (t & 63) << 2;   // 0..252
    const float* src = (mm < DD) ? (h + (size_t)(row0 + rr) * DD + mm)
                                 : (agg + (size_t)(row0 + rr) * DD + (mm - DD));
    *(float4*)&scat[rr][mm] = *(const float4*)src;
  }
  __syncthreads();
  float2 acc = *(const float2*)(ub + c2);
  #pragma unroll 4
  for (int m = 0; m < 2 * DD; ++m) {
    float a = scat[r][m];
    float2 wv = *(const float2*)(W + m * DD + c2);
    acc.x = fmaf(a, wv.x, acc.x);
    acc.y = fmaf(a, wv.y, acc.y);
  }
  float s1 = sum64(acc.x + acc.y);
  float s2 = sum64(fmaf(acc.x, acc.x, acc.y * acc.y));
  float mean = s1 * 0.0078125f;
  float var = fmaf(-mean, mean, s2 * 0.0078125f);
  float rstd = rsqrtf(var + 1e-5f);
  float2 g  = *(const float2*)(ug + c2);
  float2 be = *(const float2*)(ube + c2);
  float2 ho = *(const float2*)&scat[r][c2];
  float2 o;
  o.x = ho.x + siluf(fmaf((acc.x - mean) * rstd, g.x, be.x));
  o.y = ho.y + siluf(fmaf((acc.y - mean) * rstd, g.y, be.y));
  *(float2*)(h + (size_t)(row0 + r) * DD + c2) = o;
}

// decoder: 64 edges/block tiled GEMM (see R4 notes)
__global__ __launch_bounds__(256, 2) void k_decoder(
    const int* __restrict__ ei, const float* __restrict__ ea,
    const float* __restrict__ P, const float* __restrict__ Q,
    const float* __restrict__ w1e, const float* __restrict__ b1,
    const float* __restrict__ W2, const float* __restrict__ b2,
    const float* __restrict__ W3, const float* __restrict__ b3,
    float* __restrict__ out) {
  __shared__ float sS[64][132];
  int t = threadIdx.x;
  {
    int e = t >> 2, qq = t & 3;
    int eg = (blockIdx.x << 6) + e;
    int g0 = ei[eg], g1 = ei[NE + eg];
    float av = ea[eg];
    const float4* p4 = (const float4*)(P + (size_t)g0 * DD + qq * 32);
    const float4* q4 = (const float4*)(Q + (size_t)g1 * DD + qq * 32);
    const float4* w4 = (const float4*)(w1e + qq * 32);
    const float4* b4 = (const float4*)(b1 + qq * 32);
    #pragma unroll
    for (int m = 0; m < 8; ++m) {
      float4 p = p4[m], qv = q4[m], wvv = w4[m], bv = b4[m];
      float4 sv;
      sv.x = siluf(fmaf(av, wvv.x, (p.x + qv.x) + bv.x));
      sv.y = siluf(fmaf(av, wvv.y, (p.y + qv.y) + bv.y));
      sv.z = siluf(fmaf(av, wvv.z, (p.z + qv.z) + bv.z));
      sv.w = siluf(fmaf(av, wvv.w, (p.w + qv.w) + bv.w));
      *(float4*)&sS[e][(qq << 5) + (m << 2)] = sv;
    }
  }
  __syncthreads();
  int ti = t >> 4, tj = t & 15;
  float4 acc[4] = {{0.f,0.f,0.f,0.f},{0.f,0.f,0.f,0.f},{0.f,0.f,0.f,0.f},{0.f,0.f,0.f,0.f}};
  const float4* W2g = (const float4*)W2;
  #pragma unroll 4
  for (int k4 = 0; k4 < 32; ++k4) {
    float4 sv[4], wvv[4];
    #pragma unroll
    for (int r = 0; r < 4; ++r)
      sv[r] = *(const float4*)&sS[(ti << 2) + r][k4 << 2];
    #pragma unroll
    for (int kk = 0; kk < 4; ++kk)
      wvv[kk] = W2g[(((k4 << 2) + kk) << 4) + tj];
    #pragma unroll
    for (int r = 0; r < 4; ++r) {
      acc[r].x = fmaf(sv[r].x, wvv[0].x, acc[r].x);
      acc[r].y = fmaf(sv[r].x, wvv[0].y, acc[r].y);
      acc[r].z = fmaf(sv[r].x, wvv[0].z, acc[r].z);
      acc[r].w = fmaf(sv[r].x, wvv[0].w, acc[r].w);
      acc[r].x = fmaf(sv[r].y, wvv[1].x, acc[r].x);
      acc[r].y = fmaf(sv[r].y, wvv[1].y, acc[r].y);
      acc[r].z = fmaf(sv[r].y, wvv[1].z, acc[r].z);
      acc[r].w = fmaf(sv[r].y, wvv[1].w, acc[r].w);
      acc[r].x = fmaf(sv[r].z, wvv[2].x, acc[r].x);
      acc[r].y = fmaf(sv[r].z, wvv[2].y, acc[r].y);
      acc[r].z = fmaf(sv[r].z, wvv[2].z, acc[r].z);
      acc[r].w = fmaf(sv[r].z, wvv[2].w, acc[r].w);
      acc[r].x = fmaf(sv[r].w, wvv[3].x, acc[r].x);
      acc[r].y = fmaf(sv[r].w, wvv[3].y, acc[r].y);
      acc[r].z = fmaf(sv[r].w, wvv[3].z, acc[r].z);
      acc[r].w = fmaf(sv[r].w, wvv[3].w, acc[r].w);
    }
  }
  float4 b2v = *(const float4*)(b2 + (tj << 2));
  float4 w3v = *(const float4*)(W3 + (tj << 2));
  float b3v = b3[0];
  #pragma unroll
  for (int r = 0; r < 4; ++r) {
    float part = siluf(acc[r].x + b2v.x) * w3v.x;
    part = fmaf(siluf(acc[r].y + b2v.y), w3v.y, part);
    part = fmaf(siluf(acc[r].z + b2v.z), w3v.z, part);
    part = fmaf(siluf(acc[r].w + b2v.w), w3v.w, part);
    part = sum16(part);
    if (tj == 0)
      out[(blockIdx.x << 6) + (ti << 2) + r] = tanhf(part + b3v);
  }
}

// ---------------- launcher ----------------
extern "C" void kernel_launch(void* const* d_in, const int* in_sizes, int n_in,
                              void* d_out, int out_size, void* d_ws, size_t ws_size,
                              hipStream_t stream) {
  const float* x     = (const float*)d_in[0];
  const int*   ei    = (const int*)  d_in[1];
  const float* ea    = (const float*)d_in[2];
  const float* encW  = (const float*)d_in[4];
  const float* encb  = (const float*)d_in[5];
  const float* msgW  = (const float*)d_in[6];
  const float* msgb  = (const float*)d_in[7];
  const float* msgg  = (const float*)d_in[8];
  const float* msgbe = (const float*)d_in[9];
  const float* updW  = (const float*)d_in[10];
  const float* updb  = (const float*)d_in[11];
  const float* updg  = (const float*)d_in[12];
  const float* updbe = (const float*)d_in[13];
  const float* dW1   = (const float*)d_in[14];
  const float* db1   = (const float*)d_in[15];
  const float* dW2   = (const float*)d_in[16];
  const float* db2   = (const float*)d_in[17];
  const float* dW3   = (const float*)d_in[18];
  const float* db3   = (const float*)d_in[19];
  float* out = (float*)d_out;

  float* h     = (float*)d_ws;              // BN*DD
  float* adj   = h     + BN * DD;           // NB*NN*NN
  float* hT    = adj   + NB * NN * NN;      // BN*DD (t = h@Wt + mb; decoder P)
  float* hS    = hT    + BN * DD;           // BN*DD (s = h@Ws; decoder Q)
  float* agg   = hS    + BN * DD;           // BN*DD
  float* statT = agg   + BN * DD;           // BN*4
  float* statS = statT + BN * 4;            // BN*4
  float* wst   = statS + BN * 4;            // 8
  float* MR4   = wst   + 8;                 // NB*NN*NN*4 (rstd, -mean*rstd, a, 0)

  k_pre<<<512, 256, 0, stream>>>(x, encW, encb, msgW, h, adj, wst);
  k_scatter<<<NE / 256, 256, 0, stream>>>(ei, ea, adj);

  for (int l = 0; l < NL; ++l) {
    const float* Wl = msgW + (size_t)l * (2 * DD + 1) * DD;
    const float* wjl = Wl + 2 * DD * DD;
    k_gemm2<<<BN / 8, 512, 0, stream>>>(h, Wl, Wl + DD * DD, msgb + l * DD, wjl,
                                        hT, hS, statT, statS);
    k_ts<<<256, 256, 0, stream>>>(hT, hS, adj, statT, statS, wst + 2 * l, MR4);
    k_messages<<<1024, 512, 0, stream>>>(hT, hS, MR4, wjl,
        msgg + l * DD, msgbe + l * DD, agg);
    k_update<<<BN / 8, 512, 0, stream>>>(h, agg, updW + (size_t)l * 2 * DD * DD,
        updb + l * DD, updg + l * DD, updbe + l * DD);
  }

  k_gemm2<<<BN / 8, 512, 0, stream>>>(h, dW1, dW1 + DD * DD, nullptr, nullptr,
                                      hT, hS, statT, statS);
  k_decoder<<<NE / 64, 256, 0, stream>>>(ei, ea, hT, hS, dW1 + 2 * DD * DD, db1,
      dW2, db2, dW3, db3, out);
}

// Round 13
// 308.243 us; speedup vs baseline: 1.3006x; 1.3006x over previous
//
#include <hip/hip_runtime.h>

#define NB 16
#define NN 256
#define DD 128
#define NL 3
#define NE 32768
#define BN 4096   // NB*NN

// ---------------- helpers ----------------
__device__ __forceinline__ float siluf(float y) {
  return __fdividef(y, 1.0f + __expf(-y));
}

template<int CTRL>
__device__ __forceinline__ float dpp_add(float x) {
  int v = __builtin_amdgcn_update_dpp(0, __float_as_int(x), CTRL, 0xF, 0xF, true);
  return x + __int_as_float(v);
}

__device__ __forceinline__ float sum16(float x) {
  x = dpp_add<0xB1>(x);
  x = dpp_add<0x4E>(x);
  x = dpp_add<0x141>(x);
  x = dpp_add<0x140>(x);
  return x;
}

__device__ __forceinline__ float sum32(float x) {
  x = sum16(x);
  int v = __builtin_amdgcn_ds_swizzle(__float_as_int(x), 0x401F); // xor 16
  return x + __int_as_float(v);
}

__device__ __forceinline__ float sum64(float x) {
  x = sum32(x);
  return x + __shfl_xor(x, 32, 64);
}

// ---------------- kernels ----------------

// fused: zero adj + encode h + wprep stats
__global__ __launch_bounds__(256) void k_pre(
    const float* __restrict__ x, const float* __restrict__ encW,
    const float* __restrict__ encb, const float* __restrict__ msgW,
    float* __restrict__ h, float* __restrict__ adj, float* __restrict__ wst) {
  int t = blockIdx.x * 256 + threadIdx.x;
  float4 z = make_float4(0.f, 0.f, 0.f, 0.f);
  float4* a4 = (float4*)adj;
  a4[t] = z;
  a4[t + 131072] = z;
  int i = t >> 5;
  int c = (t & 31) << 2;
  float xv = x[i];
  float4 w = *(const float4*)(encW + c);
  float4 bv = *(const float4*)(encb + c);
  float4 o;
  o.x = fmaf(xv, w.x, bv.x); o.y = fmaf(xv, w.y, bv.y);
  o.z = fmaf(xv, w.z, bv.z); o.w = fmaf(xv, w.w, bv.w);
  *(float4*)(h + (size_t)i * DD + c) = o;
  if (blockIdx.x < NL && threadIdx.x < 64) {
    int l = blockIdx.x;
    const float* wj = msgW + (size_t)l * (2 * DD + 1) * DD + 2 * DD * DD;
    int d0 = threadIdx.x << 1;
    float2 wv = *(const float2*)(wj + d0);
    float s1 = sum64(wv.x + wv.y);
    float s2 = sum64(fmaf(wv.x, wv.x, wv.y * wv.y));
    if (threadIdx.x == 0)
      *(float2*)(wst + 2 * l) = make_float2(s1 * 0.0078125f, s2 * 0.0078125f);
  }
}

__global__ __launch_bounds__(256) void k_scatter(
    const int* __restrict__ ei, const float* __restrict__ ea,
    float* __restrict__ adj) {
  int e = blockIdx.x * 256 + threadIdx.x;
  int g0 = ei[e];
  int g1 = ei[NE + e];
  float v = ea[e];
  int b = g0 >> 8;
  int s = g0 & 255;
  int d = g1 & 255;
  atomicAdd(adj + (b * NN + s) * NN + d, v);
  atomicAdd(adj + (b * NN + d) * NN + s, v);
}

// C1 = A@W1 (+bias1), C2 = A@W2; optional per-row stats vs wj.
// 512 threads = 8 waves, wave-per-row, m-dim SPLIT across wave halves:
// lanes 0-31 do m 0..63, lanes 32-63 do m 64..127 (float4 W loads kept,
// same VMEM instr count as R8 form, but 4 waves/SIMD instead of 2).
__global__ __launch_bounds__(512) void k_gemm2(
    const float* __restrict__ A, const float* __restrict__ W1,
    const float* __restrict__ W2, const float* __restrict__ bias1,
    const float* __restrict__ wj,
    float* __restrict__ C1, float* __restrict__ C2,
    float* __restrict__ statT, float* __restrict__ statS) {
  __shared__ float sa[8][128];
  int t = threadIdx.x;
  int r = t >> 6;                // wave = row
  int lane = t & 63;
  int half = lane >> 5;          // m-half
  int c4 = (lane & 31) << 2;     // col-quad
  int row0 = blockIdx.x << 3;
  if (t < 256)
    ((float4*)sa)[t] = ((const float4*)(A + (size_t)row0 * DD))[t];
  __syncthreads();
  float4 a1 = {0.f, 0.f, 0.f, 0.f}, a2 = {0.f, 0.f, 0.f, 0.f};
  int mbase = half << 6;
  #pragma unroll 4
  for (int mm = 0; mm < 64; ++mm) {
    int m = mbase + mm;
    float a = sa[r][m];
    float4 w1 = *(const float4*)(W1 + m * DD + c4);
    float4 w2 = *(const float4*)(W2 + m * DD + c4);
    a1.x = fmaf(a, w1.x, a1.x); a1.y = fmaf(a, w1.y, a1.y);
    a1.z = fmaf(a, w1.z, a1.z); a1.w = fmaf(a, w1.w, a1.w);
    a2.x = fmaf(a, w2.x, a2.x); a2.y = fmaf(a, w2.y, a2.y);
    a2.z = fmaf(a, w2.z, a2.z); a2.w = fmaf(a, w2.w, a2.w);
  }
  // combine m-halves (both halves end with the full sums)
  a1.x += __shfl_xor(a1.x, 32, 64); a1.y += __shfl_xor(a1.y, 32, 64);
  a1.z += __shfl_xor(a1.z, 32, 64); a1.w += __shfl_xor(a1.w, 32, 64);
  a2.x += __shfl_xor(a2.x, 32, 64); a2.y += __shfl_xor(a2.y, 32, 64);
  a2.z += __shfl_xor(a2.z, 32, 64); a2.w += __shfl_xor(a2.w, 32, 64);
  if (bias1) {
    float4 bv = *(const float4*)(bias1 + c4);
    a1.x += bv.x; a1.y += bv.y; a1.z += bv.z; a1.w += bv.w;
  }
  int rw = row0 + r;
  if (lane < 32) {
    *(float4*)(C1 + (size_t)rw * DD + c4) = a1;
    *(float4*)(C2 + (size_t)rw * DD + c4) = a2;
  }
  if (wj) {
    float4 wv = *(const float4*)(wj + c4);
    float s1t = sum32((a1.x + a1.y) + (a1.z + a1.w));
    float s2t = sum32(fmaf(a1.x, a1.x, a1.y * a1.y) + fmaf(a1.z, a1.z, a1.w * a1.w));
    float s3t = sum32(fmaf(a1.x, wv.x, a1.y * wv.y) + fmaf(a1.z, wv.z, a1.w * wv.w));
    float s1s = sum32((a2.x + a2.y) + (a2.z + a2.w));
    float s2s = sum32(fmaf(a2.x, a2.x, a2.y * a2.y) + fmaf(a2.z, a2.z, a2.w * a2.w));
    float s3s = sum32(fmaf(a2.x, wv.x, a2.y * wv.y) + fmaf(a2.z, wv.z, a2.w * wv.w));
    if (lane == 0) {
      const float inv = 0.0078125f;
      ((float4*)statT)[rw] = make_float4(s1t * inv, s2t * inv, s3t * inv, 0.f);
      ((float4*)statS)[rw] = make_float4(s1s * inv, s2s * inv, s3s * inv, 0.f);
    }
  }
}

// TS GEMM + closed-form LN moments: MR4[b,i,j] = (rstd, -mean*rstd, a, 0)
__global__ __launch_bounds__(256) void k_ts(
    const float* __restrict__ T, const float* __restrict__ S,
    const float* __restrict__ adj,
    const float* __restrict__ statT, const float* __restrict__ statS,
    const float* __restrict__ wst, float* __restrict__ MR4) {
  __shared__ float sT[64][64];  // k-major: sT[k][i]
  __shared__ float sS[64][64];
  int b = blockIdx.x >> 4;
  int i0 = ((blockIdx.x >> 2) & 3) << 6;
  int j0 = (blockIdx.x & 3) << 6;
  int t = threadIdx.x;
  int ti = t >> 4, tj = t & 15;
  float acc[4][4] = {};
  int sr = t >> 2, scg = t & 3;
  const float* Trow = T + ((size_t)(b * NN + i0 + sr)) * DD + scg * 16;
  const float* Srow = S + ((size_t)(b * NN + j0 + sr)) * DD + scg * 16;
  for (int kc = 0; kc < 2; ++kc) {
    __syncthreads();
    #pragma unroll
    for (int m = 0; m < 4; ++m) {
      float4 v = *(const float4*)(Trow + kc * 64 + m * 4);
      int kk = scg * 16 + m * 4;
      sT[kk + 0][sr] = v.x; sT[kk + 1][sr] = v.y;
      sT[kk + 2][sr] = v.z; sT[kk + 3][sr] = v.w;
      float4 u = *(const float4*)(Srow + kc * 64 + m * 4);
      sS[kk + 0][sr] = u.x; sS[kk + 1][sr] = u.y;
      sS[kk + 2][sr] = u.z; sS[kk + 3][sr] = u.w;
    }
    __syncthreads();
    #pragma unroll 4
    for (int k = 0; k < 64; ++k) {
      float4 rt = *(const float4*)&sT[k][ti << 2];
      float4 rs = *(const float4*)&sS[k][tj << 2];
      acc[0][0] = fmaf(rt.x, rs.x, acc[0][0]);
      acc[0][1] = fmaf(rt.x, rs.y, acc[0][1]);
      acc[0][2] = fmaf(rt.x, rs.z, acc[0][2]);
      acc[0][3] = fmaf(rt.x, rs.w, acc[0][3]);
      acc[1][0] = fmaf(rt.y, rs.x, acc[1][0]);
      acc[1][1] = fmaf(rt.y, rs.y, acc[1][1]);
      acc[1][2] = fmaf(rt.y, rs.z, acc[1][2]);
      acc[1][3] = fmaf(rt.y, rs.w, acc[1][3]);
      acc[2][0] = fmaf(rt.z, rs.x, acc[2][0]);
      acc[2][1] = fmaf(rt.z, rs.y, acc[2][1]);
      acc[2][2] = fmaf(rt.z, rs.z, acc[2][2]);
      acc[2][3] = fmaf(rt.z, rs.w, acc[2][3]);
      acc[3][0] = fmaf(rt.w, rs.x, acc[3][0]);
      acc[3][1] = fmaf(rt.w, rs.y, acc[3][1]);
      acc[3][2] = fmaf(rt.w, rs.z, acc[3][2]);
      acc[3][3] = fmaf(rt.w, rs.w, acc[3][3]);
    }
  }
  float2 ws = *(const float2*)wst;
  float4 stT[4], stS[4];
  #pragma unroll
  for (int o = 0; o < 4; ++o) {
    stT[o] = ((const float4*)statT)[b * NN + i0 + (ti << 2) + o];
    stS[o] = ((const float4*)statS)[b * NN + j0 + (tj << 2) + o];
  }
  #pragma unroll
  for (int oi = 0; oi < 4; ++oi) {
    int row = b * NN + i0 + (ti << 2) + oi;
    float4 av = *(const float4*)(adj + (size_t)row * NN + j0 + (tj << 2));
    float4* m4row = (float4*)MR4 + (size_t)row * NN + j0 + (tj << 2);
    #pragma unroll
    for (int oj = 0; oj < 4; ++oj) {
      float a = (oj == 0) ? av.x : (oj == 1) ? av.y : (oj == 2) ? av.z : av.w;
      float mean = stT[oi].x + stS[oj].x + a * ws.x;
      float e2 = stT[oi].y + stS[oj].y + a * a * ws.y
               + fmaf(acc[oi][oj], 0.015625f, 2.f * a * (stT[oi].z + stS[oj].z));
      float var = fmaf(-mean, mean, e2);
      float Rv = rsqrtf(var + 1e-5f);
      m4row[oj] = make_float4(Rv, -mean * Rv, a, 0.f);
    }
  }
}

// message body: given MR float4 (m4) and hs float4, accumulate silu terms.
#define MSG_BODY(m4, hs, SGN)                                   \
  do {                                                          \
    float v0 = fmaf((m4).z, wv.x, tv.x + (hs).x);               \
    float v1 = fmaf((m4).z, wv.y, tv.y + (hs).y);               \
    float v2 = fmaf((m4).z, wv.z, tv.z + (hs).z);               \
    float v3 = fmaf((m4).z, wv.w, tv.w + (hs).w);               \
    float z0 = fmaf((m4).x, v0, (m4).y);                        \
    float z1 = fmaf((m4).x, v1, (m4).y);                        \
    float z2 = fmaf((m4).x, v2, (m4).y);                        \
    float z3 = fmaf((m4).x, v3, (m4).y);                        \
    float y0 = fmaf(G0, z0, B0);                                \
    float y1 = fmaf(G1, z1, B1);                                \
    float y2 = fmaf(G2, z2, B2);                                \
    float y3 = fmaf(G3, z3, B3);                                \
    float e0 = __builtin_amdgcn_exp2f(-y0);                     \
    float e1 = __builtin_amdgcn_exp2f(-y1);                     \
    float e2 = __builtin_amdgcn_exp2f(-y2);                     \
    float e3 = __builtin_amdgcn_exp2f(-y3);                     \
    float d0v = 1.0f + e0, d1v = 1.0f + e1;                     \
    float d2v = 1.0f + e2, d3v = 1.0f + e3;                     \
    float r01 = __builtin_amdgcn_rcpf(d0v * d1v);               \
    float r23 = __builtin_amdgcn_rcpf(d2v * d3v);               \
    a0 = fmaf(y0 * d1v, (SGN) * r01, a0);                       \
    a1 = fmaf(y1 * d0v, (SGN) * r01, a1);                       \
    a2 = fmaf(y2 * d3v, (SGN) * r23, a2);                       \
    a3 = fmaf(y3 * d2v, (SGN) * r23, a3);                       \
  } while (0)

// messages + aggregation: 8 waves = 2 i-pairs x 4 contiguous 64-j slices.
// hs direct from global with a 4-deep register prefetch queue; MR from LDS;
// no barriers in the hot loop.
__global__ __launch_bounds__(512, 4) void k_messages(
    const float* __restrict__ hT, const float* __restrict__ hS,
    const float* __restrict__ MR4, const float* __restrict__ wj,
    const float* __restrict__ mg, const float* __restrict__ mbe,
    float* __restrict__ agg) {
  __shared__ float4 smr[4 * 256];    // 16 KB: MR for 4 i x 256 j (then merge buf)
  const float LN2 = 0.6931471805599453f;
  const float L2E = 1.4426950408889634f;
  int b = blockIdx.x >> 6;
  int i0 = (blockIdx.x & 63) << 2;   // 4 i per block
  int t = threadIdx.x;
  int w = t >> 6, lane = t & 63;
  int p = w >> 2;                    // i-pair 0..1
  int q = w & 3;                     // 64-j slice 0..3
  int half = lane >> 5, li = lane & 31;
  int iloc = (p << 1) + half;
  int i = i0 + iloc;
  int row = b * NN + i;
  int d0 = li << 2;                  // 4 d's per lane
  float4 tv = *(const float4*)(hT + (size_t)row * DD + d0);  // includes mb
  float4 wv = *(const float4*)(wj + d0);
  float4 gv = *(const float4*)(mg + d0);
  float4 be = *(const float4*)(mbe + d0);
  float G0 = gv.x * L2E, G1 = gv.y * L2E, G2 = gv.z * L2E, G3 = gv.w * L2E;
  float B0 = be.x * L2E, B1 = be.y * L2E, B2 = be.z * L2E, B3 = be.w * L2E;
  float a0 = 0.f, a1 = 0.f, a2 = 0.f, a3 = 0.f;

  {  // stage MR for 4 i's: 1024 float4, 2 per thread (coalesced)
    const float4* msrc = (const float4*)MR4 + (size_t)(b * NN + i0) * NN;
    smr[t] = msrc[t];
    smr[t + 512] = msrc[t + 512];
  }
  __syncthreads();

  const float4* mrow = smr + (iloc << 8) + (q << 6);
  const float4* hrow = (const float4*)(hS + (size_t)(b * NN + (q << 6)) * DD) + li;

  // 4-deep register prefetch queue for hs
  float4 hsq[4];
  hsq[0] = hrow[0];
  hsq[1] = hrow[1 << 5];
  hsq[2] = hrow[2 << 5];
  hsq[3] = hrow[3 << 5];
  #pragma unroll 4
  for (int jj = 0; jj < 60; ++jj) {
    float4 hs = hsq[jj & 3];
    hsq[jj & 3] = hrow[(jj + 4) << 5];
    float4 m4 = mrow[jj];
    MSG_BODY(m4, hs, 1.0f);
  }
  #pragma unroll
  for (int jj = 60; jj < 64; ++jj) {
    float4 hs = hsq[jj & 3];
    float4 m4 = mrow[jj];
    MSG_BODY(m4, hs, 1.0f);
  }
  if ((i >> 6) == q) {  // subtract j == i (uniform per half-wave)
    float4 m4 = smr[(iloc << 8) + i];
    float4 hs = ((const float4*)(hS + (size_t)(b * NN + i) * DD))[li];
    MSG_BODY(m4, hs, -1.0f);
  }
  __syncthreads();  // all smr reads done; reuse as merge buffer
  float4* smg = (float4*)smr;
  smg[(((iloc << 2) + q) << 5) + li] = make_float4(a0, a1, a2, a3);
  __syncthreads();
  if (t < 128) {
    int il2 = t >> 5, l2 = t & 31;
    float4 s0 = smg[(((il2 << 2) + 0) << 5) + l2];
    float4 s1 = smg[(((il2 << 2) + 1) << 5) + l2];
    float4 s2 = smg[(((il2 << 2) + 2) << 5) + l2];
    float4 s3 = smg[(((il2 << 2) + 3) << 5) + l2];
    float4 o;
    o.x = ((s0.x + s1.x) + (s2.x + s3.x)) * LN2;
    o.y = ((s0.y + s1.y) + (s2.y + s3.y)) * LN2;
    o.z = ((s0.z + s1.z) + (s2.z + s3.z)) * LN2;
    o.w = ((s0.w + s1.w) + (s2.w + s3.w)) * LN2;
    *(float4*)(agg + (size_t)(b * NN + i0 + il2) * DD + (l2 << 2)) = o;
  }
}

// u = [h|agg] @ W + ub;  h += silu(LN(u))
// 512 threads = 8 waves, wave-per-row, m-dim split across wave halves
// (lanes 0-31: m 0..127, lanes 32-63: m 128..255), float4 W loads.
__global__ __launch_bounds__(512) void k_update(
    float* __restrict__ h, const float* __restrict__ agg,
    const float* __restrict__ W, const float* __restrict__ ub,
    const float* __restrict__ ug, const float* __restrict__ ube) {
  __shared__ float scat[8][256];
  int t = threadIdx.x;
  int r = t >> 6;
  int lane = t & 63;
  int half = lane >> 5;
  int c4 = (lane & 31) << 2;
  int row0 = blockIdx.x << 3;
  {
    int rr = t >> 6;
    int mm = (t & 63) << 2;   // 0..252
    const float* src = (mm < DD) ? (h + (size_t)(row0 + rr) * DD + mm)
                                 : (agg + (size_t)(row0 + rr) * DD + (mm - DD));
    *(float4*)&scat[rr][mm] = *(const float4*)src;
  }
  __syncthreads();
  float4 acc = {0.f, 0.f, 0.f, 0.f};
  int mbase = half << 7;
  #pragma unroll 4
  for (int mm = 0; mm < 128; ++mm) {
    int m = mbase + mm;
    float a = scat[r][m];
    float4 wv = *(const float4*)(W + m * DD + c4);
    acc.x = fmaf(a, wv.x, acc.x);
    acc.y = fmaf(a, wv.y, acc.y);
    acc.z = fmaf(a, wv.z, acc.z);
    acc.w = fmaf(a, wv.w, acc.w);
  }
  acc.x += __shfl_xor(acc.x, 32, 64);
  acc.y += __shfl_xor(acc.y, 32, 64);
  acc.z += __shfl_xor(acc.z, 32, 64);
  acc.w += __shfl_xor(acc.w, 32, 64);
  float4 ubv = *(const float4*)(ub + c4);
  acc.x += ubv.x; acc.y += ubv.y; acc.z += ubv.z; acc.w += ubv.w;
  float s1 = sum32((acc.x + acc.y) + (acc.z + acc.w));
  float s2 = sum32(fmaf(acc.x, acc.x, acc.y * acc.y) + fmaf(acc.z, acc.z, acc.w * acc.w));
  float mean = s1 * 0.0078125f;
  float var = fmaf(-mean, mean, s2 * 0.0078125f);
  float rstd = rsqrtf(var + 1e-5f);
  float4 g  = *(const float4*)(ug + c4);
  float4 be = *(const float4*)(ube + c4);
  if (lane < 32) {
    float4 ho = *(const float4*)&scat[r][c4];
    float4 o;
    o.x = ho.x + siluf(fmaf((acc.x - mean) * rstd, g.x, be.x));
    o.y = ho.y + siluf(fmaf((acc.y - mean) * rstd, g.y, be.y));
    o.z = ho.z + siluf(fmaf((acc.z - mean) * rstd, g.z, be.z));
    o.w = ho.w + siluf(fmaf((acc.w - mean) * rstd, g.w, be.w));
    *(float4*)(h + (size_t)(row0 + r) * DD + c4) = o;
  }
}

// decoder: 64 edges/block tiled GEMM (see R4 notes)
__global__ __launch_bounds__(256, 2) void k_decoder(
    const int* __restrict__ ei, const float* __restrict__ ea,
    const float* __restrict__ P, const float* __restrict__ Q,
    const float* __restrict__ w1e, const float* __restrict__ b1,
    const float* __restrict__ W2, const float* __restrict__ b2,
    const float* __restrict__ W3, const float* __restrict__ b3,
    float* __restrict__ out) {
  __shared__ float sS[64][132];
  int t = threadIdx.x;
  {
    int e = t >> 2, qq = t & 3;
    int eg = (blockIdx.x << 6) + e;
    int g0 = ei[eg], g1 = ei[NE + eg];
    float av = ea[eg];
    const float4* p4 = (const float4*)(P + (size_t)g0 * DD + qq * 32);
    const float4* q4 = (const float4*)(Q + (size_t)g1 * DD + qq * 32);
    const float4* w4 = (const float4*)(w1e + qq * 32);
    const float4* b4 = (const float4*)(b1 + qq * 32);
    #pragma unroll
    for (int m = 0; m < 8; ++m) {
      float4 p = p4[m], qv = q4[m], wvv = w4[m], bv = b4[m];
      float4 sv;
      sv.x = siluf(fmaf(av, wvv.x, (p.x + qv.x) + bv.x));
      sv.y = siluf(fmaf(av, wvv.y, (p.y + qv.y) + bv.y));
      sv.z = siluf(fmaf(av, wvv.z, (p.z + qv.z) + bv.z));
      sv.w = siluf(fmaf(av, wvv.w, (p.w + qv.w) + bv.w));
      *(float4*)&sS[e][(qq << 5) + (m << 2)] = sv;
    }
  }
  __syncthreads();
  int ti = t >> 4, tj = t & 15;
  float4 acc[4] = {{0.f,0.f,0.f,0.f},{0.f,0.f,0.f,0.f},{0.f,0.f,0.f,0.f},{0.f,0.f,0.f,0.f}};
  const float4* W2g = (const float4*)W2;
  #pragma unroll 4
  for (int k4 = 0; k4 < 32; ++k4) {
    float4 sv[4], wvv[4];
    #pragma unroll
    for (int r = 0; r < 4; ++r)
      sv[r] = *(const float4*)&sS[(ti << 2) + r][k4 << 2];
    #pragma unroll
    for (int kk = 0; kk < 4; ++kk)
      wvv[kk] = W2g[(((k4 << 2) + kk) << 4) + tj];
    #pragma unroll
    for (int r = 0; r < 4; ++r) {
      acc[r].x = fmaf(sv[r].x, wvv[0].x, acc[r].x);
      acc[r].y = fmaf(sv[r].x, wvv[0].y, acc[r].y);
      acc[r].z = fmaf(sv[r].x, wvv[0].z, acc[r].z);
      acc[r].w = fmaf(sv[r].x, wvv[0].w, acc[r].w);
      acc[r].x = fmaf(sv[r].y, wvv[1].x, acc[r].x);
      acc[r].y = fmaf(sv[r].y, wvv[1].y, acc[r].y);
      acc[r].z = fmaf(sv[r].y, wvv[1].z, acc[r].z);
      acc[r].w = fmaf(sv[r].y, wvv[1].w, acc[r].w);
      acc[r].x = fmaf(sv[r].z, wvv[2].x, acc[r].x);
      acc[r].y = fmaf(sv[r].z, wvv[2].y, acc[r].y);
      acc[r].z = fmaf(sv[r].z, wvv[2].z, acc[r].z);
      acc[r].w = fmaf(sv[r].z, wvv[2].w, acc[r].w);
      acc[r].x = fmaf(sv[r].w, wvv[3].x, acc[r].x);
      acc[r].y = fmaf(sv[r].w, wvv[3].y, acc[r].y);
      acc[r].z = fmaf(sv[r].w, wvv[3].z, acc[r].z);
      acc[r].w = fmaf(sv[r].w, wvv[3].w, acc[r].w);
    }
  }
  float4 b2v = *(const float4*)(b2 + (tj << 2));
  float4 w3v = *(const float4*)(W3 + (tj << 2));
  float b3v = b3[0];
  #pragma unroll
  for (int r = 0; r < 4; ++r) {
    float part = siluf(acc[r].x + b2v.x) * w3v.x;
    part = fmaf(siluf(acc[r].y + b2v.y), w3v.y, part);
    part = fmaf(siluf(acc[r].z + b2v.z), w3v.z, part);
    part = fmaf(siluf(acc[r].w + b2v.w), w3v.w, part);
    part = sum16(part);
    if (tj == 0)
      out[(blockIdx.x << 6) + (ti << 2) + r] = tanhf(part + b3v);
  }
}

// ---------------- launcher ----------------
extern "C" void kernel_launch(void* const* d_in, const int* in_sizes, int n_in,
                              void* d_out, int out_size, void* d_ws, size_t ws_size,
                              hipStream_t stream) {
  const float* x     = (const float*)d_in[0];
  const int*   ei    = (const int*)  d_in[1];
  const float* ea    = (const float*)d_in[2];
  const float* encW  = (const float*)d_in[4];
  const float* encb  = (const float*)d_in[5];
  const float* msgW  = (const float*)d_in[6];
  const float* msgb  = (const float*)d_in[7];
  const float* msgg  = (const float*)d_in[8];
  const float* msgbe = (const float*)d_in[9];
  const float* updW  = (const float*)d_in[10];
  const float* updb  = (const float*)d_in[11];
  const float* updg  = (const float*)d_in[12];
  const float* updbe = (const float*)d_in[13];
  const float* dW1   = (const float*)d_in[14];
  const float* db1   = (const float*)d_in[15];
  const float* dW2   = (const float*)d_in[16];
  const float* db2   = (const float*)d_in[17];
  const float* dW3   = (const float*)d_in[18];
  const float* db3   = (const float*)d_in[19];
  float* out = (float*)d_out;

  float* h     = (float*)d_ws;              // BN*DD
  float* adj   = h     + BN * DD;           // NB*NN*NN
  float* hT    = adj   + NB * NN * NN;      // BN*DD (t = h@Wt + mb; decoder P)
  float* hS    = hT    + BN * DD;           // BN*DD (s = h@Ws; decoder Q)
  float* agg   = hS    + BN * DD;           // BN*DD
  float* statT = agg   + BN * DD;           // BN*4
  float* statS = statT + BN * 4;            // BN*4
  float* wst   = statS + BN * 4;            // 8
  float* MR4   = wst   + 8;                 // NB*NN*NN*4 (rstd, -mean*rstd, a, 0)

  k_pre<<<512, 256, 0, stream>>>(x, encW, encb, msgW, h, adj, wst);
  k_scatter<<<NE / 256, 256, 0, stream>>>(ei, ea, adj);

  for (int l = 0; l < NL; ++l) {
    const float* Wl = msgW + (size_t)l * (2 * DD + 1) * DD;
    const float* wjl = Wl + 2 * DD * DD;
    k_gemm2<<<BN / 8, 512, 0, stream>>>(h, Wl, Wl + DD * DD, msgb + l * DD, wjl,
                                        hT, hS, statT, statS);
    k_ts<<<256, 256, 0, stream>>>(hT, hS, adj, statT, statS, wst + 2 * l, MR4);
    k_messages<<<1024, 512, 0, stream>>>(hT, hS, MR4, wjl,
        msgg + l * DD, msgbe + l * DD, agg);
    k_update<<<BN / 8, 512, 0, stream>>>(h, agg, updW + (size_t)l * 2 * DD * DD,
        updb + l * DD, updg + l * DD, updbe + l * DD);
  }

  k_gemm2<<<BN / 8, 512, 0, stream>>>(h, dW1, dW1 + DD * DD, nullptr, nullptr,
                                      hT, hS, statT, statS);
  k_decoder<<<NE / 64, 256, 0, stream>>>(ei, ea, hT, hS, dW1 + 2 * DD * DD, db1,
      dW2, db2, dW3, db3, out);
}